// Round 3
// baseline (835.143 us; speedup 1.0000x reference)
//
#include <hip/hip_runtime.h>
#include <math.h>

#define B_ 4
#define S_ 2048
#define D_ 512
#define H_ 8

typedef __attribute__((ext_vector_type(8))) short bf16x8;
typedef __attribute__((ext_vector_type(4))) float f32x4;

#define MFMA16(A, Bm, C) __builtin_amdgcn_mfma_f32_16x16x32_bf16((A), (Bm), (C), 0, 0, 0)

__device__ __forceinline__ short f2b(float f) {
  union { float f; unsigned u; } x;
  x.f = f;
  unsigned r = x.u + 0x7fffu + ((x.u >> 16) & 1u);
  return (short)(r >> 16);
}

// ---------------------------------------------------------------------------
// prep: W[512x512] fp32 (k-major) -> Wt[n][k] bf16 (transposed), z picks matrix
// ---------------------------------------------------------------------------
__global__ __launch_bounds__(256) void prep_wt(
    const float* __restrict__ Wq, const float* __restrict__ Wk,
    const float* __restrict__ Wv, const float* __restrict__ Wo,
    short* __restrict__ Wqt, short* __restrict__ Wkt,
    short* __restrict__ Wvt, short* __restrict__ Wot)
{
  const float* W; short* Wt;
  switch (blockIdx.z) {
    case 0: W = Wq; Wt = Wqt; break;
    case 1: W = Wk; Wt = Wkt; break;
    case 2: W = Wv; Wt = Wvt; break;
    default: W = Wo; Wt = Wot; break;
  }
  __shared__ float Ws[64 * 68];
  const int t = threadIdx.x;
  const int n0 = blockIdx.x * 64, k0 = blockIdx.y * 64;

  #pragma unroll
  for (int rep = 0; rep < 4; ++rep) {
    int e4 = rep * 256 + t;
    int r = e4 >> 4, c0 = (e4 & 15) * 4;
    *(float4*)&Ws[r * 68 + c0] = *(const float4*)&W[(size_t)(k0 + r) * 512 + n0 + c0];
  }
  __syncthreads();

  int rn = t >> 2;
  int kb = (t & 3) * 16;
  union { short s[8]; int4 v; } pk;
  #pragma unroll
  for (int half = 0; half < 2; ++half) {
    #pragma unroll
    for (int i = 0; i < 8; ++i)
      pk.s[i] = f2b(Ws[(kb + half * 8 + i) * 68 + rn]);
    *(int4*)&Wt[(size_t)(n0 + rn) * 512 + k0 + kb + half * 8] = pk.v;
  }
}

// ---------------------------------------------------------------------------
// QKV projection, MFMA bf16. Tile 64m x 128n. X[8192x512] fp32, Wt[n][k] bf16.
// z=0 -> qh (pre-scaled by 0.125), z=1 -> kh, z=2 -> vt[bh][d][2048]
// ---------------------------------------------------------------------------
__global__ __launch_bounds__(256) void qkv_mfma(
    const float* __restrict__ q, const float* __restrict__ k, const float* __restrict__ v,
    const short* __restrict__ Wqt, const short* __restrict__ Wkt, const short* __restrict__ Wvt,
    short* __restrict__ qh, short* __restrict__ kh, short* __restrict__ vt)
{
  const int z = blockIdx.z;
  const float* X = (z == 0) ? q : (z == 1) ? k : v;
  const short* Wt = (z == 0) ? Wqt : (z == 1) ? Wkt : Wvt;

  __shared__ short Xs[64 * 72];
  __shared__ short Wsh[128 * 72];

  const int t = threadIdx.x;
  const int wave = t >> 6, lane = t & 63, quad = lane >> 4, l15 = lane & 15;
  const int tile_n = blockIdx.x * 128;
  const int tile_m = blockIdx.y * 64;

  f32x4 acc[8];
  #pragma unroll
  for (int nt = 0; nt < 8; ++nt) acc[nt] = (f32x4){0.f, 0.f, 0.f, 0.f};

  for (int k0 = 0; k0 < 512; k0 += 64) {
    __syncthreads();
    #pragma unroll
    for (int rep = 0; rep < 4; ++rep) {
      int e4 = rep * 256 + t;
      int row = e4 >> 4, c0 = (e4 & 15) * 4;
      float4 xv = *(const float4*)&X[(size_t)(tile_m + row) * 512 + k0 + c0];
      *(short4*)&Xs[row * 72 + c0] =
          make_short4(f2b(xv.x), f2b(xv.y), f2b(xv.z), f2b(xv.w));
    }
    #pragma unroll
    for (int rep = 0; rep < 4; ++rep) {
      int e = rep * 256 + t;
      int row = e >> 3, c0 = (e & 7) * 8;
      *(int4*)&Wsh[row * 72 + c0] = *(const int4*)&Wt[(size_t)(tile_n + row) * 512 + k0 + c0];
    }
    __syncthreads();
    #pragma unroll
    for (int ks = 0; ks < 2; ++ks) {
      bf16x8 af = *(bf16x8*)&Xs[(wave * 16 + l15) * 72 + ks * 32 + quad * 8];
      #pragma unroll
      for (int nt = 0; nt < 8; ++nt) {
        bf16x8 bfr = *(bf16x8*)&Wsh[(nt * 16 + l15) * 72 + ks * 32 + quad * 8];
        acc[nt] = MFMA16(af, bfr, acc[nt]);
      }
    }
  }

  const float scale = (z == 0) ? 0.125f : 1.0f;
  if (z < 2) {
    short* Y = (z == 0) ? qh : kh;
    #pragma unroll
    for (int nt = 0; nt < 8; ++nt) {
      int d = tile_n + nt * 16 + l15;
      int h = d >> 6, dd = d & 63;
      #pragma unroll
      for (int r = 0; r < 4; ++r) {
        int row = tile_m + wave * 16 + quad * 4 + r;
        int b = row >> 11, s = row & (S_ - 1);
        Y[(((size_t)(b * H_ + h)) * S_ + s) * 64 + dd] = f2b(acc[nt][r] * scale);
      }
    }
  } else {
    int row0 = tile_m + wave * 16 + quad * 4;
    int b = row0 >> 11, s0 = row0 & (S_ - 1);
    #pragma unroll
    for (int nt = 0; nt < 8; ++nt) {
      int d = tile_n + nt * 16 + l15;
      int h = d >> 6, dd = d & 63;
      short4 pk = make_short4(f2b(acc[nt][0]), f2b(acc[nt][1]),
                              f2b(acc[nt][2]), f2b(acc[nt][3]));
      *(short4*)&vt[(((size_t)(b * H_ + h)) * 64 + dd) * S_ + s0] = pk;
    }
  }
}

// ---------------------------------------------------------------------------
// Fused attention, MFMA bf16. Block = (64 q-rows, one bh). Two passes over K.
// qh (pre-scaled)/kh: [bh][s][64] bf16 ; vt: [bh][d][2048] bf16.
// Masked score -1e-9 => exp == 1.0f exactly, so contribution = fma(mm, e-1, 1).
// Diagonal override only exists in the k-tile kt0==q0 (and only nt==wave).
// ---------------------------------------------------------------------------
__global__ __launch_bounds__(256) void attn_mfma(
    const short* __restrict__ qh, const short* __restrict__ kh,
    const short* __restrict__ vt, const int* __restrict__ src_mask,
    float* __restrict__ attn_out, short* __restrict__ ohb)
{
  const int t = threadIdx.x;
  const int wave = t >> 6, lane = t & 63, quad = lane >> 4, l15 = lane & 15;
  const int q0 = blockIdx.x * 64;
  const int bh = blockIdx.y, b = bh >> 3, h = bh & 7;

  __shared__ short Ks[64 * 72];
  __shared__ short Vs[64 * 72];
  __shared__ short Ps[64 * 72];     // Q staging at init, P tile in pass B
  __shared__ float smqf[64], smkf[64];

  #pragma unroll
  for (int rep = 0; rep < 2; ++rep) {
    int e = rep * 256 + t;
    int row = e >> 3, c0 = (e & 7) * 8;
    *(int4*)&Ps[row * 72 + c0] =
        *(const int4*)&qh[((size_t)bh * S_ + q0 + row) * 64 + c0];
  }
  if (t < 64) smqf[t] = (float)src_mask[b * S_ + q0 + t];
  __syncthreads();

  bf16x8 qf[2];
  #pragma unroll
  for (int ks = 0; ks < 2; ++ks)
    qf[ks] = *(bf16x8*)&Ps[(wave * 16 + l15) * 72 + ks * 32 + quad * 8];

  int rloc[4];
  float mqf[4];
  #pragma unroll
  for (int r = 0; r < 4; ++r) {
    rloc[r] = wave * 16 + quad * 4 + r;
    mqf[r] = smqf[rloc[r]];
  }

  // ---------------- Pass A: exp-sums ----------------
  // init 128 = (4 nt * 32 tiles) accounts for the "+1" of every element
  float rs[4] = {128.f, 128.f, 128.f, 128.f};
  for (int kt0 = 0; kt0 < S_; kt0 += 64) {
    __syncthreads();
    #pragma unroll
    for (int rep = 0; rep < 2; ++rep) {
      int e = rep * 256 + t;
      int row = e >> 3, c0 = (e & 7) * 8;
      *(int4*)&Ks[row * 72 + c0] =
          *(const int4*)&kh[((size_t)bh * S_ + kt0 + row) * 64 + c0];
    }
    if (t < 64) smkf[t] = (float)src_mask[b * S_ + kt0 + t];
    __syncthreads();

    const bool diagtile = (kt0 == q0);
    #pragma unroll
    for (int nt = 0; nt < 4; ++nt) {
      f32x4 c = (f32x4){0.f, 0.f, 0.f, 0.f};
      #pragma unroll
      for (int ks = 0; ks < 2; ++ks) {
        bf16x8 kf = *(bf16x8*)&Ks[(nt * 16 + l15) * 72 + ks * 32 + quad * 8];
        c = MFMA16(qf[ks], kf, c);
      }
      float mk = smkf[nt * 16 + l15];
      if (diagtile && nt == wave) {
        #pragma unroll
        for (int r = 0; r < 4; ++r) {
          float e = __expf(c[r]);
          float mm = mqf[r] * mk;
          float pun = fmaf(mm, e - 1.f, 1.f);
          if (l15 == quad * 4 + r) pun = e;      // diagonal forced keep
          rs[r] += pun - 1.f;
        }
      } else {
        #pragma unroll
        for (int r = 0; r < 4; ++r) {
          float e = __expf(c[r]);
          float mm = mqf[r] * mk;
          rs[r] = fmaf(mm, e - 1.f, rs[r]);
        }
      }
    }
  }
  #pragma unroll
  for (int r = 0; r < 4; ++r) {
    float vsum = rs[r];
    vsum += __shfl_xor(vsum, 1);
    vsum += __shfl_xor(vsum, 2);
    vsum += __shfl_xor(vsum, 4);
    vsum += __shfl_xor(vsum, 8);
    rs[r] = 1.f / vsum;
  }

  // ---------------- Pass B: attn write + PV ----------------
  f32x4 oacc[4];
  #pragma unroll
  for (int dt = 0; dt < 4; ++dt) oacc[dt] = (f32x4){0.f, 0.f, 0.f, 0.f};

  float* arow[4];
  #pragma unroll
  for (int r = 0; r < 4; ++r)
    arow[r] = attn_out + ((size_t)bh * S_ + q0 + rloc[r]) * S_;

  for (int kt0 = 0; kt0 < S_; kt0 += 64) {
    __syncthreads();
    #pragma unroll
    for (int rep = 0; rep < 2; ++rep) {
      int e = rep * 256 + t;
      int row = e >> 3, c0 = (e & 7) * 8;
      *(int4*)&Ks[row * 72 + c0] =
          *(const int4*)&kh[((size_t)bh * S_ + kt0 + row) * 64 + c0];
      *(int4*)&Vs[row * 72 + c0] =
          *(const int4*)&vt[((size_t)bh * 64 + row) * S_ + kt0 + c0];
    }
    if (t < 64) smkf[t] = (float)src_mask[b * S_ + kt0 + t];
    __syncthreads();

    const bool diagtile = (kt0 == q0);
    #pragma unroll
    for (int nt = 0; nt < 4; ++nt) {
      f32x4 c = (f32x4){0.f, 0.f, 0.f, 0.f};
      #pragma unroll
      for (int ks = 0; ks < 2; ++ks) {
        bf16x8 kf = *(bf16x8*)&Ks[(nt * 16 + l15) * 72 + ks * 32 + quad * 8];
        c = MFMA16(qf[ks], kf, c);
      }
      float mk = smkf[nt * 16 + l15];
      int kj = kt0 + nt * 16 + l15;
      if (diagtile && nt == wave) {
        #pragma unroll
        for (int r = 0; r < 4; ++r) {
          float e = __expf(c[r]);
          float mm = mqf[r] * mk;
          float pun = fmaf(mm, e - 1.f, 1.f);
          if (l15 == quad * 4 + r) pun = e;
          float p = pun * rs[r];
          arow[r][kj] = p;
          Ps[rloc[r] * 72 + nt * 16 + l15] = f2b(p);
        }
      } else {
        #pragma unroll
        for (int r = 0; r < 4; ++r) {
          float e = __expf(c[r]);
          float mm = mqf[r] * mk;
          float pun = fmaf(mm, e - 1.f, 1.f);
          float p = pun * rs[r];
          arow[r][kj] = p;
          Ps[rloc[r] * 72 + nt * 16 + l15] = f2b(p);
        }
      }
    }
    __syncthreads();

    bf16x8 pf[2];
    #pragma unroll
    for (int ks = 0; ks < 2; ++ks)
      pf[ks] = *(bf16x8*)&Ps[(wave * 16 + l15) * 72 + ks * 32 + quad * 8];
    #pragma unroll
    for (int dt = 0; dt < 4; ++dt) {
      #pragma unroll
      for (int ks = 0; ks < 2; ++ks) {
        bf16x8 vf = *(bf16x8*)&Vs[(dt * 16 + l15) * 72 + ks * 32 + quad * 8];
        oacc[dt] = MFMA16(pf[ks], vf, oacc[dt]);
      }
    }
  }

  #pragma unroll
  for (int dt = 0; dt < 4; ++dt) {
    int d = h * 64 + dt * 16 + l15;
    #pragma unroll
    for (int r = 0; r < 4; ++r)
      ohb[((size_t)b * S_ + q0 + rloc[r]) * 512 + d] = f2b(oacc[dt][r]);
  }
}

// ---------------------------------------------------------------------------
// out = ohb @ Wo + residual(q), MFMA bf16, fp32 out.
// ---------------------------------------------------------------------------
__global__ __launch_bounds__(256) void out_mfma(
    const short* __restrict__ ohb, const short* __restrict__ Wot,
    const float* __restrict__ resid, float* __restrict__ out)
{
  __shared__ short Xs[64 * 72];
  __shared__ short Wsh[128 * 72];

  const int t = threadIdx.x;
  const int wave = t >> 6, lane = t & 63, quad = lane >> 4, l15 = lane & 15;
  const int tile_n = blockIdx.x * 128;
  const int tile_m = blockIdx.y * 64;

  f32x4 acc[8];
  #pragma unroll
  for (int nt = 0; nt < 8; ++nt) acc[nt] = (f32x4){0.f, 0.f, 0.f, 0.f};

  for (int k0 = 0; k0 < 512; k0 += 64) {
    __syncthreads();
    #pragma unroll
    for (int rep = 0; rep < 2; ++rep) {
      int e = rep * 256 + t;
      int row = e >> 3, c0 = (e & 7) * 8;
      *(int4*)&Xs[row * 72 + c0] = *(const int4*)&ohb[(size_t)(tile_m + row) * 512 + k0 + c0];
    }
    #pragma unroll
    for (int rep = 0; rep < 4; ++rep) {
      int e = rep * 256 + t;
      int row = e >> 3, c0 = (e & 7) * 8;
      *(int4*)&Wsh[row * 72 + c0] = *(const int4*)&Wot[(size_t)(tile_n + row) * 512 + k0 + c0];
    }
    __syncthreads();
    #pragma unroll
    for (int ks = 0; ks < 2; ++ks) {
      bf16x8 af = *(bf16x8*)&Xs[(wave * 16 + l15) * 72 + ks * 32 + quad * 8];
      #pragma unroll
      for (int nt = 0; nt < 8; ++nt) {
        bf16x8 bfr = *(bf16x8*)&Wsh[(nt * 16 + l15) * 72 + ks * 32 + quad * 8];
        acc[nt] = MFMA16(af, bfr, acc[nt]);
      }
    }
  }

  #pragma unroll
  for (int nt = 0; nt < 8; ++nt) {
    int c = tile_n + nt * 16 + l15;
    #pragma unroll
    for (int r = 0; r < 4; ++r) {
      size_t row = tile_m + wave * 16 + quad * 4 + r;
      out[row * 512 + c] = acc[nt][r] + resid[row * 512 + c];
    }
  }
}

// ---------------------------------------------------------------------------
// LayerNorm over last dim (512), one wave per row, in place.
// ---------------------------------------------------------------------------
__global__ __launch_bounds__(256) void ln_kernel(
    float* __restrict__ io, const float* __restrict__ gamma, const float* __restrict__ beta)
{
  const int wid  = threadIdx.x >> 6;
  const int lane = threadIdx.x & 63;
  const size_t row = (size_t)blockIdx.x * 4 + wid;
  const size_t base = row * 512 + lane * 8;

  float4 x0 = *(const float4*)&io[base];
  float4 x1 = *(const float4*)&io[base + 4];
  float xs[8] = {x0.x, x0.y, x0.z, x0.w, x1.x, x1.y, x1.z, x1.w};

  float s = 0.f, s2 = 0.f;
  #pragma unroll
  for (int i = 0; i < 8; ++i) { s += xs[i]; s2 = fmaf(xs[i], xs[i], s2); }
  #pragma unroll
  for (int m = 1; m < 64; m <<= 1) {
    s  += __shfl_xor(s, m);
    s2 += __shfl_xor(s2, m);
  }
  float mu  = s * (1.f / 512.f);
  float var = s2 * (1.f / 512.f) - mu * mu;
  float rsq = rsqrtf(var + 1e-6f);

  float4 g0 = *(const float4*)&gamma[lane * 8];
  float4 g1 = *(const float4*)&gamma[lane * 8 + 4];
  float4 b0 = *(const float4*)&beta[lane * 8];
  float4 b1 = *(const float4*)&beta[lane * 8 + 4];
  float gs[8] = {g0.x, g0.y, g0.z, g0.w, g1.x, g1.y, g1.z, g1.w};
  float bs[8] = {b0.x, b0.y, b0.z, b0.w, b1.x, b1.y, b1.z, b1.w};

  float ys[8];
  #pragma unroll
  for (int i = 0; i < 8; ++i) ys[i] = (xs[i] - mu) * rsq * gs[i] + bs[i];
  *(float4*)&io[base]     = make_float4(ys[0], ys[1], ys[2], ys[3]);
  *(float4*)&io[base + 4] = make_float4(ys[4], ys[5], ys[6], ys[7]);
}

// ---------------------------------------------------------------------------
extern "C" void kernel_launch(void* const* d_in, const int* in_sizes, int n_in,
                              void* d_out, int out_size, void* d_ws, size_t ws_size,
                              hipStream_t stream)
{
  const float* q     = (const float*)d_in[0];
  const float* k     = (const float*)d_in[1];
  const float* v     = (const float*)d_in[2];
  const int*  smask  = (const int*)d_in[3];
  const float* Wq    = (const float*)d_in[4];
  const float* Wk    = (const float*)d_in[5];
  const float* Wv    = (const float*)d_in[6];
  const float* Wo    = (const float*)d_in[7];
  const float* gamma = (const float*)d_in[8];
  const float* beta  = (const float*)d_in[9];

  float* out  = (float*)d_out;
  float* attn = out + (size_t)B_ * S_ * D_;

  short* wsS = (short*)d_ws;
  short* qh  = wsS;                    // [32 bh][2048][64]
  short* kh  = qh + 4194304;
  short* vt  = kh + 4194304;           // [32 bh][64][2048]
  short* ohb = vt + 4194304;           // [8192][512]
  short* Wqt = ohb + 4194304;          // [512][512] each
  short* Wkt = Wqt + 262144;
  short* Wvt = Wkt + 262144;
  short* Wot = Wvt + 262144;

  prep_wt<<<dim3(8, 8, 4), 256, 0, stream>>>(Wq, Wk, Wv, Wo, Wqt, Wkt, Wvt, Wot);
  qkv_mfma<<<dim3(4, 128, 3), 256, 0, stream>>>(q, k, v, Wqt, Wkt, Wvt, qh, kh, vt);
  attn_mfma<<<dim3(32, 32), 256, 0, stream>>>(qh, kh, vt, smask, attn, ohb);
  out_mfma<<<dim3(4, 128), 256, 0, stream>>>(ohb, Wot, q, out);
  ln_kernel<<<2048, 256, 0, stream>>>(out, gamma, beta);
}